// Round 1
// baseline (871.543 us; speedup 1.0000x reference)
//
#include <hip/hip_runtime.h>

// Kalman-style linear recurrence, exact chunked-scan parallelization.
//   M = A - L*H ;  x_{k+1} = M x_k + L y_k ;  out_k = H x_k
// C = 64 steps/chunk, P = N/64 chunks. Lookback depth 8 with P64 = M^64.
//
// R3: multi-chunk-per-wave latency amortization. rocprof R2: VALUBusy 39%,
// occupancy ~2.9 waves/CU, HBM 2% -> per-step period ~1600cyc is exposed
// serial latency (FMA chain -> ds_write -> lgkm -> ds_read), not issue work.
// Each wave now advances G independent chunks per step (G=2 phase3, G=4
// phase1), sharing Mrow/Hrow registers; states packed as float{G} per lane
// in LDS so one ds_write + broadcast b128 reads feed all G chunks.
// Lookback made uniform D=8 via 512-float zero pad before bvec.
// Requires Nv % 64 == 0 (true here: 200000 = 3125*64).

#define CHUNK 64
#define LOOKBACK 8

// ---------------------------------------------------------------- setup ----
__global__ __launch_bounds__(1024) void kf_setup(const float* __restrict__ A,
                                                 const float* __restrict__ Hm,
                                                 const float* __restrict__ Lp,
                                                 float* __restrict__ ws) {
  __shared__ __align__(16) float s0[64 * 68];
  __shared__ __align__(16) float s1[64 * 68];
  const float Lg = Lp[0];
  const int t  = threadIdx.x;      // 0..1023
  const int r  = t >> 4;           // 0..63
  const int c0 = (t & 15) * 4;     // 0,4,..,60

  // zero pad region ws[4096 .. 4607] (lookback reads b[c<0] as 0)
  if (t < 512) ws[4096 + t] = 0.f;

  {
    const float4 a4 = *(const float4*)(A  + r * 64 + c0);
    const float4 h4 = *(const float4*)(Hm + r * 64 + c0);
    float4 m4;
    m4.x = fmaf(-Lg, h4.x, a4.x);
    m4.y = fmaf(-Lg, h4.y, a4.y);
    m4.z = fmaf(-Lg, h4.z, a4.z);
    m4.w = fmaf(-Lg, h4.w, a4.w);
    *(float4*)(s0 + r * 68 + c0) = m4;
  }
  __syncthreads();

  float* src = s0;
  float* dst = s1;
  for (int sq = 0; sq < 6; ++sq) {           // M^2, M^4, ... M^64
    float4 acc = make_float4(0.f, 0.f, 0.f, 0.f);
    const float* srow = src + r * 68;
    #pragma unroll 8
    for (int k = 0; k < 64; ++k) {
      const float  a  = srow[k];
      const float4 b4 = *(const float4*)(src + k * 68 + c0);
      acc.x = fmaf(a, b4.x, acc.x);
      acc.y = fmaf(a, b4.y, acc.y);
      acc.z = fmaf(a, b4.z, acc.z);
      acc.w = fmaf(a, b4.w, acc.w);
    }
    __syncthreads();
    *(float4*)(dst + r * 68 + c0) = acc;
    __syncthreads();
    float* tmp = src; src = dst; dst = tmp;
  }
  *(float4*)(ws + r * 64 + c0) = *(const float4*)(src + r * 68 + c0);
}

// --------------------------------------------------------------- phase 1 ----
// G=4 chunks per 1-wave block. xs[lane] = {x0,x1,x2,x3}; each broadcast
// b128 read of xs[j] feeds 4 FMAs (one per chunk).
__global__ __launch_bounds__(64, 1) void kf_phase1(const float* __restrict__ y,
                                                   const float* __restrict__ A,
                                                   const float* __restrict__ Hm,
                                                   const float* __restrict__ Lp,
                                                   float* __restrict__ bb,
                                                   int Nv, int P) {
  const int lane = threadIdx.x;
  const int cb   = blockIdx.x * 4;
  const float Lg = Lp[0];
  __shared__ __align__(16) float4 xs[64];

  float Mrow[64];
  {
    const float* Ar = A  + lane * 64;
    const float* Hr = Hm + lane * 64;
    #pragma unroll
    for (int j = 0; j < 64; j += 4) {
      const float4 a4 = *(const float4*)(Ar + j);
      const float4 h4 = *(const float4*)(Hr + j);
      Mrow[j + 0] = fmaf(-Lg, h4.x, a4.x);
      Mrow[j + 1] = fmaf(-Lg, h4.y, a4.y);
      Mrow[j + 2] = fmaf(-Lg, h4.z, a4.z);
      Mrow[j + 3] = fmaf(-Lg, h4.w, a4.w);
    }
  }

  const int c0 = min(cb + 0, P - 1);
  const int c1 = min(cb + 1, P - 1);
  const int c2 = min(cb + 2, P - 1);
  const int c3 = min(cb + 3, P - 1);
  const float* y0 = y + (size_t)lane * (size_t)Nv + c0 * CHUNK;
  const float* y1 = y + (size_t)lane * (size_t)Nv + c1 * CHUNK;
  const float* y2 = y + (size_t)lane * (size_t)Nv + c2 * CHUNK;
  const float* y3 = y + (size_t)lane * (size_t)Nv + c3 * CHUNK;

  float x0 = 0.f, x1 = 0.f, x2 = 0.f, x3 = 0.f;

  #pragma unroll 1
  for (int t = 0; t < 8; ++t) {
    const float4 pa0 = *(const float4*)(y0 + 8 * t);
    const float4 pb0 = *(const float4*)(y0 + 8 * t + 4);
    const float4 pa1 = *(const float4*)(y1 + 8 * t);
    const float4 pb1 = *(const float4*)(y1 + 8 * t + 4);
    const float4 pa2 = *(const float4*)(y2 + 8 * t);
    const float4 pb2 = *(const float4*)(y2 + 8 * t + 4);
    const float4 pa3 = *(const float4*)(y3 + 8 * t);
    const float4 pb3 = *(const float4*)(y3 + 8 * t + 4);
    float yb0[8] = {pa0.x, pa0.y, pa0.z, pa0.w, pb0.x, pb0.y, pb0.z, pb0.w};
    float yb1[8] = {pa1.x, pa1.y, pa1.z, pa1.w, pb1.x, pb1.y, pb1.z, pb1.w};
    float yb2[8] = {pa2.x, pa2.y, pa2.z, pa2.w, pb2.x, pb2.y, pb2.z, pb2.w};
    float yb3[8] = {pa3.x, pa3.y, pa3.z, pa3.w, pb3.x, pb3.y, pb3.z, pb3.w};

    #pragma unroll
    for (int kk = 0; kk < 8; ++kk) {
      xs[lane] = make_float4(x0, x1, x2, x3);
      __syncthreads();
      float a0 = 0.f, a1 = 0.f, a2 = 0.f, a3 = 0.f;
      #pragma unroll
      for (int j = 0; j < 64; ++j) {
        const float4 v = xs[j];
        a0 = fmaf(Mrow[j], v.x, a0);
        a1 = fmaf(Mrow[j], v.y, a1);
        a2 = fmaf(Mrow[j], v.z, a2);
        a3 = fmaf(Mrow[j], v.w, a3);
      }
      __syncthreads();
      x0 = fmaf(Lg, yb0[kk], a0);
      x1 = fmaf(Lg, yb1[kk], a1);
      x2 = fmaf(Lg, yb2[kk], a2);
      x3 = fmaf(Lg, yb3[kk], a3);
    }
  }
  bb[c0 * 64 + lane] = x0;
  bb[c1 * 64 + lane] = x1;
  bb[c2 * 64 + lane] = x2;
  bb[c3 * 64 + lane] = x3;
}

// --------------------------------------------------------------- phase 3 ----
// G=2 chunks per 1-wave block. xs[lane] = {x0,x1}; paired b128 reads cover
// two j's for both chunks -> 32 reads, 256 FMAs (8 chains) per step.
__global__ __launch_bounds__(64, 1) void kf_phase3(const float* __restrict__ y,
                                                   const float* __restrict__ A,
                                                   const float* __restrict__ Hm,
                                                   const float* __restrict__ Lp,
                                                   const float* __restrict__ bb,
                                                   const float* __restrict__ P64,
                                                   float* __restrict__ out,
                                                   int Nv, int P) {
  const int lane = threadIdx.x;
  const int cb   = blockIdx.x * 2;
  const int c0   = min(cb + 0, P - 1);
  const int c1   = min(cb + 1, P - 1);
  const float Lg = Lp[0];
  __shared__ __align__(16) float2 xs[64];

  float Mrow[64];
  {
    const float* Ar = A  + lane * 64;
    const float* Hr = Hm + lane * 64;
    #pragma unroll
    for (int j = 0; j < 64; j += 4) {
      const float4 a4 = *(const float4*)(Ar + j);
      const float4 h4 = *(const float4*)(Hr + j);
      Mrow[j + 0] = fmaf(-Lg, h4.x, a4.x);
      Mrow[j + 1] = fmaf(-Lg, h4.y, a4.y);
      Mrow[j + 2] = fmaf(-Lg, h4.z, a4.z);
      Mrow[j + 3] = fmaf(-Lg, h4.w, a4.w);
    }
  }

  // ---- lookback, uniform depth 8 (bb has 512-float zero pad in front):
  //      s_c = b[c-1] + P64*(b[c-2] + P64*(... b[c-8]))
  float x0, x1;
  {
    float Prow[64];  // lifetime ends before Hrow loads; allocator reuses
    #pragma unroll
    for (int j = 0; j < 64; j += 4) {
      const float4 p4 = *(const float4*)(P64 + lane * 64 + j);
      Prow[j + 0] = p4.x; Prow[j + 1] = p4.y;
      Prow[j + 2] = p4.z; Prow[j + 3] = p4.w;
    }
    x0 = bb[(c0 - LOOKBACK) * 64 + lane];
    x1 = bb[(c1 - LOOKBACK) * 64 + lane];
    #pragma unroll 1
    for (int t = LOOKBACK - 1; t >= 1; --t) {
      xs[lane] = make_float2(x0, x1);
      __syncthreads();
      float p0 = 0.f, p1 = 0.f, q0 = 0.f, q1 = 0.f;
      #pragma unroll
      for (int jj = 0; jj < 32; ++jj) {
        const float4 v = ((const float4*)xs)[jj];
        p0 = fmaf(Prow[2 * jj + 0], v.x, p0);
        p1 = fmaf(Prow[2 * jj + 0], v.y, p1);
        q0 = fmaf(Prow[2 * jj + 1], v.z, q0);
        q1 = fmaf(Prow[2 * jj + 1], v.w, q1);
      }
      __syncthreads();
      x0 = p0 + q0 + bb[(c0 - t) * 64 + lane];
      x1 = p1 + q1 + bb[(c1 - t) * 64 + lane];
    }
  }

  float Hrow[64];
  #pragma unroll
  for (int j = 0; j < 64; j += 4) {
    const float4 h4 = *(const float4*)(Hm + lane * 64 + j);
    Hrow[j + 0] = h4.x; Hrow[j + 1] = h4.y;
    Hrow[j + 2] = h4.z; Hrow[j + 3] = h4.w;
  }

  const float* yr0 = y   + (size_t)lane * (size_t)Nv + c0 * CHUNK;
  const float* yr1 = y   + (size_t)lane * (size_t)Nv + c1 * CHUNK;
  float*       o0  = out + (size_t)lane * (size_t)Nv + c0 * CHUNK;
  float*       o1  = out + (size_t)lane * (size_t)Nv + c1 * CHUNK;

  #pragma unroll 1
  for (int t = 0; t < 8; ++t) {
    const float4 pa0 = *(const float4*)(yr0 + 8 * t);
    const float4 pb0 = *(const float4*)(yr0 + 8 * t + 4);
    const float4 pa1 = *(const float4*)(yr1 + 8 * t);
    const float4 pb1 = *(const float4*)(yr1 + 8 * t + 4);
    float yb0[8] = {pa0.x, pa0.y, pa0.z, pa0.w, pb0.x, pb0.y, pb0.z, pb0.w};
    float yb1[8] = {pa1.x, pa1.y, pa1.z, pa1.w, pb1.x, pb1.y, pb1.z, pb1.w};
    float ob0[8], ob1[8];

    #pragma unroll
    for (int kk = 0; kk < 8; ++kk) {
      xs[lane] = make_float2(x0, x1);
      __syncthreads();
      float h0e = 0.f, h1e = 0.f, m0e = 0.f, m1e = 0.f;
      float h0o = 0.f, h1o = 0.f, m0o = 0.f, m1o = 0.f;
      #pragma unroll
      for (int jj = 0; jj < 32; ++jj) {
        const float4 v = ((const float4*)xs)[jj];
        h0e = fmaf(Hrow[2 * jj + 0], v.x, h0e);
        h1e = fmaf(Hrow[2 * jj + 0], v.y, h1e);
        m0e = fmaf(Mrow[2 * jj + 0], v.x, m0e);
        m1e = fmaf(Mrow[2 * jj + 0], v.y, m1e);
        h0o = fmaf(Hrow[2 * jj + 1], v.z, h0o);
        h1o = fmaf(Hrow[2 * jj + 1], v.w, h1o);
        m0o = fmaf(Mrow[2 * jj + 1], v.z, m0o);
        m1o = fmaf(Mrow[2 * jj + 1], v.w, m1o);
      }
      __syncthreads();
      ob0[kk] = h0e + h0o;
      ob1[kk] = h1e + h1o;
      x0 = fmaf(Lg, yb0[kk], m0e + m0o);
      x1 = fmaf(Lg, yb1[kk], m1e + m1o);
    }
    *(float4*)(o0 + 8 * t)     = make_float4(ob0[0], ob0[1], ob0[2], ob0[3]);
    *(float4*)(o0 + 8 * t + 4) = make_float4(ob0[4], ob0[5], ob0[6], ob0[7]);
    *(float4*)(o1 + 8 * t)     = make_float4(ob1[0], ob1[1], ob1[2], ob1[3]);
    *(float4*)(o1 + 8 * t + 4) = make_float4(ob1[4], ob1[5], ob1[6], ob1[7]);
  }
}

// ---------------------------------------------------------------------------
extern "C" void kernel_launch(void* const* d_in, const int* in_sizes, int n_in,
                              void* d_out, int out_size, void* d_ws, size_t ws_size,
                              hipStream_t stream) {
  const float* y  = (const float*)d_in[0];
  const float* A  = (const float*)d_in[1];
  const float* Hm = (const float*)d_in[2];
  const float* Lp = (const float*)d_in[3];
  const int Nv = in_sizes[0] / 64;          // 200000 (multiple of 64)
  const int P  = (Nv + CHUNK - 1) / CHUNK;  // 3125

  float* ws   = (float*)d_ws;
  float* P64  = ws;                  // 4096 floats
  float* bb   = ws + 4096 + 512;     // bvec; 512-float zero pad in front

  kf_setup<<<1, 1024, 0, stream>>>(A, Hm, Lp, ws);
  kf_phase1<<<(P + 3) / 4, 64, 0, stream>>>(y, A, Hm, Lp, bb, Nv, P);
  kf_phase3<<<(P + 1) / 2, 64, 0, stream>>>(y, A, Hm, Lp, bb, P64, (float*)d_out, Nv, P);
}

// Round 2
// 263.379 us; speedup vs baseline: 3.3091x; 3.3091x over previous
//
#include <hip/hip_runtime.h>

// Kalman-style linear recurrence, exact chunked-scan parallelization.
//   M = A - L*H ;  x_{k+1} = M x_k + L y_k ;  out_k = H x_k
// C = 64 steps/chunk, P = N/64 chunks. Lookback depth 8 with P64 = M^64.
//
// R4: readlane broadcast. R3 lesson: arch-VGPR hard cap is 256 for VALU-only
// code (512 budget = VGPR+AGPR unified); G=2 spilled ~26 regs/lane/step to
// scratch (FETCH 750MB, VALUBusy 9%). Revert to 1 chunk/wave; instead kill
// the per-step serial LDS round-trip (x -> ds_write -> barrier -> ds_read,
// ~1600cyc measured period): blocks are ONE wave and x is one value/lane, so
// broadcast x[j] via v_readlane_b32 (compile-time lane idx) -> no LDS, no
// barrier, no lgkmcnt in the main loop. Per step: 64 readlane + 128 FMA
// (phase3; readlane feeds both H-dot and M-dot). Issue-bound floor ~31us.

#define CHUNK 64
#define LOOKBACK 8

__device__ __forceinline__ float bcast(float x, int l) {
  return __uint_as_float(__builtin_amdgcn_readlane(__float_as_uint(x), l));
}

// ---------------------------------------------------------------- setup ----
__global__ __launch_bounds__(1024) void kf_setup(const float* __restrict__ A,
                                                 const float* __restrict__ Hm,
                                                 const float* __restrict__ Lp,
                                                 float* __restrict__ ws) {
  __shared__ __align__(16) float s0[64 * 68];
  __shared__ __align__(16) float s1[64 * 68];
  const float Lg = Lp[0];
  const int t  = threadIdx.x;      // 0..1023
  const int r  = t >> 4;           // 0..63
  const int c0 = (t & 15) * 4;     // 0,4,..,60

  // zero pad region ws[4096 .. 4607] (lookback reads b[c<0] as 0)
  if (t < 512) ws[4096 + t] = 0.f;

  {
    const float4 a4 = *(const float4*)(A  + r * 64 + c0);
    const float4 h4 = *(const float4*)(Hm + r * 64 + c0);
    float4 m4;
    m4.x = fmaf(-Lg, h4.x, a4.x);
    m4.y = fmaf(-Lg, h4.y, a4.y);
    m4.z = fmaf(-Lg, h4.z, a4.z);
    m4.w = fmaf(-Lg, h4.w, a4.w);
    *(float4*)(s0 + r * 68 + c0) = m4;
  }
  __syncthreads();

  float* src = s0;
  float* dst = s1;
  for (int sq = 0; sq < 6; ++sq) {           // M^2, M^4, ... M^64
    float4 acc = make_float4(0.f, 0.f, 0.f, 0.f);
    const float* srow = src + r * 68;
    #pragma unroll 8
    for (int k = 0; k < 64; ++k) {
      const float  a  = srow[k];
      const float4 b4 = *(const float4*)(src + k * 68 + c0);
      acc.x = fmaf(a, b4.x, acc.x);
      acc.y = fmaf(a, b4.y, acc.y);
      acc.z = fmaf(a, b4.z, acc.z);
      acc.w = fmaf(a, b4.w, acc.w);
    }
    __syncthreads();
    *(float4*)(dst + r * 68 + c0) = acc;
    __syncthreads();
    float* tmp = src; src = dst; dst = tmp;
  }
  *(float4*)(ws + r * 64 + c0) = *(const float4*)(src + r * 68 + c0);
}

// --------------------------------------------------------------- phase 1 ----
// One chunk per 1-wave block. x distributed (1 VGPR); broadcast via readlane.
__global__ __launch_bounds__(64, 4) void kf_phase1(const float* __restrict__ y,
                                                   const float* __restrict__ A,
                                                   const float* __restrict__ Hm,
                                                   const float* __restrict__ Lp,
                                                   float* __restrict__ bb,
                                                   int Nv) {
  const int c    = blockIdx.x;
  const int lane = threadIdx.x;
  const float Lg = Lp[0];

  float Mrow[64];
  {
    const float* Ar = A  + lane * 64;
    const float* Hr = Hm + lane * 64;
    #pragma unroll
    for (int j = 0; j < 64; j += 4) {
      const float4 a4 = *(const float4*)(Ar + j);
      const float4 h4 = *(const float4*)(Hr + j);
      Mrow[j + 0] = fmaf(-Lg, h4.x, a4.x);
      Mrow[j + 1] = fmaf(-Lg, h4.y, a4.y);
      Mrow[j + 2] = fmaf(-Lg, h4.z, a4.z);
      Mrow[j + 3] = fmaf(-Lg, h4.w, a4.w);
    }
  }

  const int k0 = c * CHUNK;
  const float* yrow = y + (size_t)lane * (size_t)Nv + k0;
  const int nst = min(CHUNK, Nv - k0);
  float x = 0.f;

  if (nst == CHUNK) {
    #pragma unroll 1
    for (int t = 0; t < 8; ++t) {
      const float4 p0 = *(const float4*)(yrow + 8 * t);
      const float4 p1 = *(const float4*)(yrow + 8 * t + 4);
      const float yb[8] = {p0.x, p0.y, p0.z, p0.w, p1.x, p1.y, p1.z, p1.w};
      #pragma unroll
      for (int kk = 0; kk < 8; ++kk) {
        float a0 = 0.f, a1 = 0.f, a2 = 0.f, a3 = 0.f;
        #pragma unroll
        for (int j = 0; j < 64; j += 4) {
          const float s0 = bcast(x, j + 0);
          const float s1 = bcast(x, j + 1);
          const float s2 = bcast(x, j + 2);
          const float s3 = bcast(x, j + 3);
          a0 = fmaf(Mrow[j + 0], s0, a0);
          a1 = fmaf(Mrow[j + 1], s1, a1);
          a2 = fmaf(Mrow[j + 2], s2, a2);
          a3 = fmaf(Mrow[j + 3], s3, a3);
        }
        x = fmaf(Lg, yb[kk], (a0 + a1) + (a2 + a3));
      }
    }
  } else {
    for (int kk = 0; kk < nst; ++kk) {
      float a0 = 0.f, a1 = 0.f, a2 = 0.f, a3 = 0.f;
      #pragma unroll
      for (int j = 0; j < 64; j += 4) {
        const float s0 = bcast(x, j + 0);
        const float s1 = bcast(x, j + 1);
        const float s2 = bcast(x, j + 2);
        const float s3 = bcast(x, j + 3);
        a0 = fmaf(Mrow[j + 0], s0, a0);
        a1 = fmaf(Mrow[j + 1], s1, a1);
        a2 = fmaf(Mrow[j + 2], s2, a2);
        a3 = fmaf(Mrow[j + 3], s3, a3);
      }
      x = fmaf(Lg, yrow[kk], (a0 + a1) + (a2 + a3));
    }
  }
  bb[c * 64 + lane] = x;
}

// --------------------------------------------------------------- phase 3 ----
// One chunk per 1-wave block; readlane broadcast feeds both H and M dots.
__global__ __launch_bounds__(64, 2) void kf_phase3(const float* __restrict__ y,
                                                   const float* __restrict__ A,
                                                   const float* __restrict__ Hm,
                                                   const float* __restrict__ Lp,
                                                   const float* __restrict__ bb,
                                                   const float* __restrict__ P64,
                                                   float* __restrict__ out,
                                                   int Nv) {
  const int c    = blockIdx.x;
  const int lane = threadIdx.x;
  const float Lg = Lp[0];

  float Mrow[64];
  {
    const float* Ar = A  + lane * 64;
    const float* Hr = Hm + lane * 64;
    #pragma unroll
    for (int j = 0; j < 64; j += 4) {
      const float4 a4 = *(const float4*)(Ar + j);
      const float4 h4 = *(const float4*)(Hr + j);
      Mrow[j + 0] = fmaf(-Lg, h4.x, a4.x);
      Mrow[j + 1] = fmaf(-Lg, h4.y, a4.y);
      Mrow[j + 2] = fmaf(-Lg, h4.z, a4.z);
      Mrow[j + 3] = fmaf(-Lg, h4.w, a4.w);
    }
  }

  // ---- lookback, uniform depth 8 (bb has 512-float zero pad in front):
  //      s_c = b[c-1] + P64*(b[c-2] + P64*(... b[c-8]))
  float x;
  {
    float Prow[64];  // lifetime ends before Hrow loads; allocator reuses
    #pragma unroll
    for (int j = 0; j < 64; j += 4) {
      const float4 p4 = *(const float4*)(P64 + lane * 64 + j);
      Prow[j + 0] = p4.x; Prow[j + 1] = p4.y;
      Prow[j + 2] = p4.z; Prow[j + 3] = p4.w;
    }
    x = bb[(c - LOOKBACK) * 64 + lane];
    #pragma unroll 1
    for (int t = LOOKBACK - 1; t >= 1; --t) {
      float a0 = 0.f, a1 = 0.f, a2 = 0.f, a3 = 0.f;
      #pragma unroll
      for (int j = 0; j < 64; j += 4) {
        const float s0 = bcast(x, j + 0);
        const float s1 = bcast(x, j + 1);
        const float s2 = bcast(x, j + 2);
        const float s3 = bcast(x, j + 3);
        a0 = fmaf(Prow[j + 0], s0, a0);
        a1 = fmaf(Prow[j + 1], s1, a1);
        a2 = fmaf(Prow[j + 2], s2, a2);
        a3 = fmaf(Prow[j + 3], s3, a3);
      }
      x = (a0 + a1) + (a2 + a3) + bb[(c - t) * 64 + lane];
    }
  }

  float Hrow[64];
  #pragma unroll
  for (int j = 0; j < 64; j += 4) {
    const float4 h4 = *(const float4*)(Hm + lane * 64 + j);
    Hrow[j + 0] = h4.x; Hrow[j + 1] = h4.y;
    Hrow[j + 2] = h4.z; Hrow[j + 3] = h4.w;
  }

  const int k0 = c * CHUNK;
  const float* yrow = y   + (size_t)lane * (size_t)Nv + k0;
  float*       orow = out + (size_t)lane * (size_t)Nv + k0;
  const int nst = min(CHUNK, Nv - k0);

  if (nst == CHUNK) {
    #pragma unroll 1
    for (int t = 0; t < 8; ++t) {
      const float4 p0 = *(const float4*)(yrow + 8 * t);
      const float4 p1 = *(const float4*)(yrow + 8 * t + 4);
      const float yb[8] = {p0.x, p0.y, p0.z, p0.w, p1.x, p1.y, p1.z, p1.w};
      float ob[8];
      #pragma unroll
      for (int kk = 0; kk < 8; ++kk) {
        float h0 = 0.f, h1 = 0.f, h2 = 0.f, h3 = 0.f;
        float m0 = 0.f, m1 = 0.f, m2 = 0.f, m3 = 0.f;
        #pragma unroll
        for (int j = 0; j < 64; j += 4) {
          const float s0 = bcast(x, j + 0);
          const float s1 = bcast(x, j + 1);
          const float s2 = bcast(x, j + 2);
          const float s3 = bcast(x, j + 3);
          h0 = fmaf(Hrow[j + 0], s0, h0);
          m0 = fmaf(Mrow[j + 0], s0, m0);
          h1 = fmaf(Hrow[j + 1], s1, h1);
          m1 = fmaf(Mrow[j + 1], s1, m1);
          h2 = fmaf(Hrow[j + 2], s2, h2);
          m2 = fmaf(Mrow[j + 2], s2, m2);
          h3 = fmaf(Hrow[j + 3], s3, h3);
          m3 = fmaf(Mrow[j + 3], s3, m3);
        }
        ob[kk] = (h0 + h1) + (h2 + h3);
        x = fmaf(Lg, yb[kk], (m0 + m1) + (m2 + m3));
      }
      *(float4*)(orow + 8 * t)     = make_float4(ob[0], ob[1], ob[2], ob[3]);
      *(float4*)(orow + 8 * t + 4) = make_float4(ob[4], ob[5], ob[6], ob[7]);
    }
  } else {
    for (int kk = 0; kk < nst; ++kk) {
      float h0 = 0.f, h1 = 0.f, h2 = 0.f, h3 = 0.f;
      float m0 = 0.f, m1 = 0.f, m2 = 0.f, m3 = 0.f;
      #pragma unroll
      for (int j = 0; j < 64; j += 4) {
        const float s0 = bcast(x, j + 0);
        const float s1 = bcast(x, j + 1);
        const float s2 = bcast(x, j + 2);
        const float s3 = bcast(x, j + 3);
        h0 = fmaf(Hrow[j + 0], s0, h0);
        m0 = fmaf(Mrow[j + 0], s0, m0);
        h1 = fmaf(Hrow[j + 1], s1, h1);
        m1 = fmaf(Mrow[j + 1], s1, m1);
        h2 = fmaf(Hrow[j + 2], s2, h2);
        m2 = fmaf(Mrow[j + 2], s2, m2);
        h3 = fmaf(Hrow[j + 3], s3, h3);
        m3 = fmaf(Mrow[j + 3], s3, m3);
      }
      orow[kk] = (h0 + h1) + (h2 + h3);
      x = fmaf(Lg, yrow[kk], (m0 + m1) + (m2 + m3));
    }
  }
}

// ---------------------------------------------------------------------------
extern "C" void kernel_launch(void* const* d_in, const int* in_sizes, int n_in,
                              void* d_out, int out_size, void* d_ws, size_t ws_size,
                              hipStream_t stream) {
  const float* y  = (const float*)d_in[0];
  const float* A  = (const float*)d_in[1];
  const float* Hm = (const float*)d_in[2];
  const float* Lp = (const float*)d_in[3];
  const int Nv = in_sizes[0] / 64;          // 200000
  const int P  = (Nv + CHUNK - 1) / CHUNK;  // 3125

  float* ws   = (float*)d_ws;
  float* P64  = ws;                  // 4096 floats
  float* bb   = ws + 4096 + 512;     // bvec; 512-float zero pad in front

  kf_setup<<<1, 1024, 0, stream>>>(A, Hm, Lp, ws);
  kf_phase1<<<P, 64, 0, stream>>>(y, A, Hm, Lp, bb, Nv);
  kf_phase3<<<P, 64, 0, stream>>>(y, A, Hm, Lp, bb, P64, (float*)d_out, Nv);
}